// Round 1
// baseline (800.584 us; speedup 1.0000x reference)
//
#include <hip/hip_runtime.h>
#include <hip/hip_bf16.h>

// ---------------- problem constants ----------------
constexpr int BATCH = 8;
constexpr int NA    = 261888;
constexpr int KSEL  = 6000;          // PRE_NMS_LIMIT
constexpr int PROP  = 1000;          // PROPOSAL_COUNT
constexpr int CAP   = 8192;          // candidate capacity (pow2 for bitonic)
constexpr int NBINS = 8192;          // histogram bins
constexpr int NB    = (KSEL + 63) / 64;   // 94 mask words per row
constexpr int CH    = 32;            // scan chunk rows
constexpr int NCH   = (KSEL + CH - 1) / CH; // 188

// workspace layout (bytes)
constexpr size_t OFF_HIST  = 0;                                   // 8*8192*4 = 262144
constexpr size_t OFF_CNT   = 262144;                              // 8*4
constexpr size_t OFF_TSEL  = 262176;                              // 8*4
constexpr size_t OFF_KEYS  = 262208;                              // 8*8192*8 = 524288
constexpr size_t OFF_BOXES = 786496;                              // 8*6000*16 = 768000
constexpr size_t OFF_MASK  = 1554496;                             // 8*94*6000*8 = 36096000
// total ~37.65 MB

__device__ __forceinline__ int score_bin(float s) {
  int b = (int)(s * (float)NBINS);
  if (b < 0) b = 0;
  if (b > NBINS - 1) b = NBINS - 1;
  return b;
}

// ---------------- 1. histogram ----------------
__global__ __launch_bounds__(256) void hist_kernel(const float2* __restrict__ probs,
                                                   unsigned int* __restrict__ hist) {
  __shared__ unsigned int lh[NBINS];
  for (int i = threadIdx.x; i < NBINS; i += blockDim.x) lh[i] = 0u;
  __syncthreads();
  int b = blockIdx.y;
  const float2* p = probs + (size_t)b * NA;
  for (int a = blockIdx.x * blockDim.x + threadIdx.x; a < NA; a += gridDim.x * blockDim.x) {
    float s = p[a].y;
    atomicAdd(&lh[score_bin(s)], 1u);
  }
  __syncthreads();
  unsigned int* gh = hist + (size_t)b * NBINS;
  for (int i = threadIdx.x; i < NBINS; i += blockDim.x) {
    unsigned int v = lh[i];
    if (v) atomicAdd(&gh[i], v);
  }
}

// ---------------- 2. threshold bin select ----------------
__global__ __launch_bounds__(256) void thresh_kernel(const unsigned int* __restrict__ hist,
                                                     int* __restrict__ tsel) {
  constexpr int GR = NBINS / 256; // 32 bins per thread
  int b = blockIdx.x;
  const unsigned int* h = hist + (size_t)b * NBINS;
  __shared__ unsigned int gsum[256];
  unsigned int s = 0;
  int g0 = threadIdx.x * GR;
  for (int i = 0; i < GR; ++i) s += h[g0 + i];
  gsum[threadIdx.x] = s;
  __syncthreads();
  if (threadIdx.x == 0) {
    unsigned int acc = 0;
    int g = 255;
    for (; g > 0; --g) {
      if (acc + gsum[g] >= (unsigned)KSEL) break;
      acc += gsum[g];
    }
    int t = g * GR;
    for (int bin = g * GR + GR - 1; bin >= g * GR; --bin) {
      acc += h[bin];
      if (acc >= (unsigned)KSEL) { t = bin; break; }
    }
    tsel[b] = t;
  }
}

// ---------------- 3. compact candidates ----------------
__global__ __launch_bounds__(256) void compact_kernel(const float2* __restrict__ probs,
                                                      const int* __restrict__ tsel,
                                                      int* __restrict__ cnt,
                                                      unsigned long long* __restrict__ keys) {
  int b = blockIdx.y;
  int t = tsel[b];
  const float2* p = probs + (size_t)b * NA;
  unsigned long long* kb = keys + (size_t)b * CAP;
  for (int a = blockIdx.x * blockDim.x + threadIdx.x; a < NA; a += gridDim.x * blockDim.x) {
    float s = p[a].y;
    if (score_bin(s) >= t) {
      int pos = atomicAdd(&cnt[b], 1);
      if (pos < CAP) {
        unsigned int ib = ~__float_as_uint(s); // score>=0: ~bits ascending == score descending
        kb[pos] = ((unsigned long long)ib << 32) | (unsigned int)a;
      }
    }
  }
}

// ---------------- 4. bitonic sort + box decode ----------------
__global__ __launch_bounds__(1024) void sortbox_kernel(const float4* __restrict__ anchors4,
                                                       const float4* __restrict__ bbox4,
                                                       const int* __restrict__ cnt,
                                                       const unsigned long long* __restrict__ keys,
                                                       float4* __restrict__ boxes4) {
#pragma clang fp contract(off)
  __shared__ unsigned long long sh[CAP];
  int b = blockIdx.x;
  int n = cnt[b];
  if (n > CAP) n = CAP;
  const unsigned long long* kb = keys + (size_t)b * CAP;
  for (int i = threadIdx.x; i < CAP; i += 1024) sh[i] = (i < n) ? kb[i] : ~0ull;
  __syncthreads();
  for (int k = 2; k <= CAP; k <<= 1) {
    for (int j = k >> 1; j > 0; j >>= 1) {
      for (int i = threadIdx.x; i < CAP; i += 1024) {
        int ixj = i ^ j;
        if (ixj > i) {
          unsigned long long a = sh[i], c = sh[ixj];
          bool up = ((i & k) == 0);
          if ((a > c) == up) { sh[i] = c; sh[ixj] = a; }
        }
      }
      __syncthreads();
    }
  }
  for (int r = threadIdx.x; r < KSEL; r += 1024) {
    int a = (int)(unsigned int)sh[r];
    float4 anc = anchors4[(size_t)b * NA + a];
    float4 d   = bbox4[(size_t)b * NA + a];
    float h = anc.z - anc.x;
    float w = anc.w - anc.y;
    float dy = d.x * 0.1f, dx = d.y * 0.1f, dh = d.z * 0.2f, dw = d.w * 0.2f;
    float cy = (anc.x + (0.5f * h)) + (dy * h);
    float cx = (anc.y + (0.5f * w)) + (dx * w);
    float h2 = h * expf(dh);
    float w2 = w * expf(dw);
    float y1 = cy - 0.5f * h2;
    float x1 = cx - 0.5f * w2;
    float y2 = y1 + h2;
    float x2 = x1 + w2;
    y1 = fminf(fmaxf(y1, 0.f), 1.f);
    x1 = fminf(fmaxf(x1, 0.f), 1.f);
    y2 = fminf(fmaxf(y2, 0.f), 1.f);
    x2 = fminf(fmaxf(x2, 0.f), 1.f);
    boxes4[(size_t)b * KSEL + r] = make_float4(y1, x1, y2, x2);
  }
}

// ---------------- 5. suppression mask matrix (transposed: [b][colblock][row]) ----------------
__global__ __launch_bounds__(64) void mask_kernel(const float4* __restrict__ boxes4,
                                                  unsigned long long* __restrict__ maskT) {
#pragma clang fp contract(off)
  int cb = blockIdx.x, rb = blockIdx.y, b = blockIdx.z;
  if (cb < rb) return;   // lower-triangle words never read by the scan
  __shared__ float4 cols[64];
  int c0 = cb * 64;
  int c = c0 + threadIdx.x;
  cols[threadIdx.x] = (c < KSEL) ? boxes4[(size_t)b * KSEL + c] : make_float4(0.f, 0.f, 0.f, 0.f);
  __syncthreads();
  int row = rb * 64 + threadIdx.x;
  if (row >= KSEL) return;
  float4 r = boxes4[(size_t)b * KSEL + row];
  float ra = (r.z - r.x) * (r.w - r.y);
  unsigned long long bits = 0ull;
  int nmax = min(64, KSEL - c0);
  for (int u = 0; u < nmax; ++u) {
    int cc = c0 + u;
    if (cc <= row) continue;
    float4 cb4 = cols[u];
    float ca = (cb4.z - cb4.x) * (cb4.w - cb4.y);
    float ih = fmaxf(fminf(r.z, cb4.z) - fmaxf(r.x, cb4.x), 0.f);
    float iw = fmaxf(fminf(r.w, cb4.w) - fmaxf(r.y, cb4.y), 0.f);
    float inter = ih * iw;
    float uni = (ra + ca) - inter;
    float iou = (uni > 0.f) ? (inter / uni) : 0.f;
    if (iou > 0.7f) bits |= (1ull << u);
  }
  maskT[((size_t)b * NB + cb) * KSEL + row] = bits;
}

// ---------------- 6. serial greedy scan + output ----------------
__global__ __launch_bounds__(256) void scan_kernel(const float4* __restrict__ boxes4,
                                                   const unsigned long long* __restrict__ maskT,
                                                   float4* __restrict__ out4) {
  __shared__ unsigned long long sbuf[2][CH][NB];
  __shared__ unsigned long long ssup[NB];
  __shared__ int skeep[PROP];
  __shared__ int s_state[2]; // [0]=kept, [1]=done
  int b = blockIdx.x;
  int tid = threadIdx.x;
  for (int i = tid; i < NB; i += 256) ssup[i] = 0ull;
  if (tid == 0) { s_state[0] = 0; s_state[1] = 0; }
  // stage chunk 0
  for (int idx = tid; idx < NB * CH; idx += 256) {
    int jw = idx / CH, u = idx % CH;
    sbuf[0][u][jw] = maskT[((size_t)b * NB + jw) * KSEL + u];
  }
  __syncthreads();
  for (int c = 0; c < NCH; ++c) {
    int cur = c & 1;
    if (tid >= 64) {
      // waves 1-3: stage chunk c+1
      int nc = c + 1;
      if (nc < NCH) {
        int base = nc * CH;
        int nrows = min(CH, KSEL - base);
        for (int idx = tid - 64; idx < NB * nrows; idx += 192) {
          int jw = idx / nrows, u = idx % nrows;
          sbuf[cur ^ 1][u][jw] = maskT[((size_t)b * NB + jw) * KSEL + base + u];
        }
      }
    } else {
      // wave 0: serial greedy over chunk c
      int base = c * CH;
      int cword = base >> 6;        // constant within chunk (CH divides 64)
      int lane = tid;
      unsigned long long cw = ssup[cword];
      int kept = s_state[0];
      int done = 0;
      int nrows = min(CH, KSEL - base);
#pragma unroll
      for (int u = 0; u < CH; ++u) {
        if (u >= nrows) break;
        unsigned long long dw = sbuf[cur][u][cword]; // unconditional: lets scheduler batch reads
        int i = base + u;
        int bit = i & 63;
        if (!((cw >> bit) & 1ull)) {
          if (lane == 0) skeep[kept] = i;
          kept++;
          if (kept >= PROP) { done = 1; break; }
          int jw = cword + lane;
          if (jw < NB) ssup[jw] |= sbuf[cur][u][jw];
          int jw2 = jw + 64;
          if (jw2 < NB) ssup[jw2] |= sbuf[cur][u][jw2];
          cw |= dw;
        }
      }
      if (lane == 0) {
        s_state[0] = kept;
        if (done || c == NCH - 1) s_state[1] = 1;
      }
    }
    __syncthreads();
    if (s_state[1]) break;
  }
  __syncthreads();
  int kept = s_state[0];
  for (int r = tid; r < PROP; r += 256) {
    float4 v = make_float4(0.f, 0.f, 0.f, 0.f);
    if (r < kept) v = boxes4[(size_t)b * KSEL + skeep[r]];
    out4[(size_t)b * PROP + r] = v;
  }
}

// ---------------- launch ----------------
extern "C" void kernel_launch(void* const* d_in, const int* in_sizes, int n_in,
                              void* d_out, int out_size, void* d_ws, size_t ws_size,
                              hipStream_t stream) {
  const float2* probs   = (const float2*)d_in[0];
  const float4* bbox4   = (const float4*)d_in[1];
  const float4* anchors4= (const float4*)d_in[2];
  float4* out4 = (float4*)d_out;
  char* ws = (char*)d_ws;

  unsigned int* hist        = (unsigned int*)(ws + OFF_HIST);
  int* cnt                  = (int*)(ws + OFF_CNT);
  int* tsel                 = (int*)(ws + OFF_TSEL);
  unsigned long long* keys  = (unsigned long long*)(ws + OFF_KEYS);
  float4* boxes4            = (float4*)(ws + OFF_BOXES);
  unsigned long long* maskT = (unsigned long long*)(ws + OFF_MASK);

  // zero hist + cnt (stale/poisoned otherwise)
  hipMemsetAsync(ws, 0, OFF_TSEL, stream);

  hipLaunchKernelGGL(hist_kernel,    dim3(128, BATCH), dim3(256), 0, stream, probs, hist);
  hipLaunchKernelGGL(thresh_kernel,  dim3(BATCH),      dim3(256), 0, stream, hist, tsel);
  hipLaunchKernelGGL(compact_kernel, dim3(128, BATCH), dim3(256), 0, stream, probs, tsel, cnt, keys);
  hipLaunchKernelGGL(sortbox_kernel, dim3(BATCH),      dim3(1024), 0, stream, anchors4, bbox4, cnt, keys, boxes4);
  hipLaunchKernelGGL(mask_kernel,    dim3(NB, NB, BATCH), dim3(64), 0, stream, boxes4, maskT);
  hipLaunchKernelGGL(scan_kernel,    dim3(BATCH),      dim3(256), 0, stream, boxes4, maskT, out4);
}

// Round 2
// 512.795 us; speedup vs baseline: 1.5612x; 1.5612x over previous
//
#include <hip/hip_runtime.h>
#include <hip/hip_bf16.h>

// ---------------- problem constants ----------------
constexpr int BATCH = 8;
constexpr int NA    = 261888;
constexpr int KSEL  = 6000;          // PRE_NMS_LIMIT
constexpr int PROP  = 1000;          // PROPOSAL_COUNT
constexpr int CAP   = 8192;          // candidate capacity (pow2 for bitonic)
constexpr int NBINS = 8192;          // histogram bins
constexpr int HB    = 16;            // private histogram blocks per batch
constexpr int NB    = (KSEL + 63) / 64;   // 94 mask words per row
constexpr int CH    = 32;            // scan chunk rows
constexpr int NCH   = (KSEL + CH - 1) / CH; // 188

// workspace layout (bytes) — hist ALIASES mask region (disjoint liveness:
// hist dies after thresh_kernel; maskT is first written by mask_kernel later)
constexpr size_t OFF_CNT   = 0;                                   // 8*16*4 = 512 (64B-spaced counters)
constexpr size_t OFF_TSEL  = 512;                                 // 32
constexpr size_t OFF_KEYS  = 544;                                 // 8*8192*8 = 524288
constexpr size_t OFF_BOXES = 524832;                              // 8*6000*16 = 768000
constexpr size_t OFF_MASK  = 1292832;                             // 8*94*6000*8 = 36096000
constexpr size_t OFF_HIST  = OFF_MASK;                            // 8*16*8192*4 = 4MB (aliased)
// total ~37.39 MB

__device__ __forceinline__ int score_bin(float s) {
  int b = (int)(s * (float)NBINS);
  if (b < 0) b = 0;
  if (b > NBINS - 1) b = NBINS - 1;
  return b;
}

// ---------------- 1. histogram (private per-block copies, no global atomics) ----------------
__global__ __launch_bounds__(256) void hist_kernel(const float2* __restrict__ probs,
                                                   unsigned int* __restrict__ hist) {
  __shared__ unsigned int lh[NBINS];
  for (int i = threadIdx.x; i < NBINS; i += 256) lh[i] = 0u;
  __syncthreads();
  int b = blockIdx.y;
  const float2* p = probs + (size_t)b * NA;
  for (int a = blockIdx.x * 256 + threadIdx.x; a < NA; a += HB * 256) {
    atomicAdd(&lh[score_bin(p[a].y)], 1u);
  }
  __syncthreads();
  unsigned int* gh = hist + ((size_t)b * HB + blockIdx.x) * NBINS;
  for (int i = threadIdx.x; i < NBINS; i += 256) gh[i] = lh[i];
}

// ---------------- 2. threshold bin select ----------------
__global__ __launch_bounds__(256) void thresh_kernel(const unsigned int* __restrict__ hist,
                                                     int* __restrict__ tsel) {
  constexpr int GR = NBINS / 256; // 32 bins per thread
  __shared__ unsigned int ch[NBINS];
  __shared__ unsigned int gsum[256];
  int b = blockIdx.x;
  const unsigned int* h = hist + (size_t)b * HB * NBINS;
  for (int bin = threadIdx.x; bin < NBINS; bin += 256) {
    unsigned int s = 0;
    for (int k = 0; k < HB; ++k) s += h[(size_t)k * NBINS + bin];
    ch[bin] = s;
  }
  __syncthreads();
  unsigned int s = 0;
  int g0 = threadIdx.x * GR;
  for (int i = 0; i < GR; ++i) s += ch[g0 + i];
  gsum[threadIdx.x] = s;
  __syncthreads();
  if (threadIdx.x == 0) {
    unsigned int acc = 0;
    int g = 255;
    for (; g > 0; --g) {
      if (acc + gsum[g] >= (unsigned)KSEL) break;
      acc += gsum[g];
    }
    int t = g * GR;
    for (int bin = g * GR + GR - 1; bin >= g * GR; --bin) {
      acc += ch[bin];
      if (acc >= (unsigned)KSEL) { t = bin; break; }
    }
    tsel[b] = t;
  }
}

// ---------------- 3. compact candidates (block-aggregated, 1 global atomic/block) ----------------
__global__ __launch_bounds__(256) void compact_kernel(const float2* __restrict__ probs,
                                                      const int* __restrict__ tsel,
                                                      int* __restrict__ cnt,
                                                      unsigned long long* __restrict__ keys) {
  __shared__ int lcnt, lbase;
  __shared__ unsigned long long lbuf[2048]; // block covers <=2048 anchors
  int b = blockIdx.y;
  int t = tsel[b];
  if (threadIdx.x == 0) lcnt = 0;
  __syncthreads();
  const float2* p = probs + (size_t)b * NA;
  for (int a = blockIdx.x * blockDim.x + threadIdx.x; a < NA; a += gridDim.x * blockDim.x) {
    float s = p[a].y;
    if (score_bin(s) >= t) {
      int pos = atomicAdd(&lcnt, 1);
      unsigned int ib = ~__float_as_uint(s); // score>=0: ~bits ascending == score descending
      lbuf[pos] = ((unsigned long long)ib << 32) | (unsigned int)a;
    }
  }
  __syncthreads();
  if (threadIdx.x == 0) lbase = atomicAdd(&cnt[b * 16], lcnt);
  __syncthreads();
  int n = lcnt, base = lbase;
  unsigned long long* kb = keys + (size_t)b * CAP;
  for (int i = threadIdx.x; i < n; i += 256) {
    int pos = base + i;
    if (pos < CAP) kb[pos] = lbuf[i];
  }
}

// ---------------- 4. bitonic sort + box decode ----------------
__global__ __launch_bounds__(1024) void sortbox_kernel(const float4* __restrict__ anchors4,
                                                       const float4* __restrict__ bbox4,
                                                       const int* __restrict__ cnt,
                                                       const unsigned long long* __restrict__ keys,
                                                       float4* __restrict__ boxes4) {
#pragma clang fp contract(off)
  __shared__ unsigned long long sh[CAP];
  int b = blockIdx.x;
  int n = cnt[b * 16];
  if (n > CAP) n = CAP;
  const unsigned long long* kb = keys + (size_t)b * CAP;
  for (int i = threadIdx.x; i < CAP; i += 1024) sh[i] = (i < n) ? kb[i] : ~0ull;
  __syncthreads();
  for (int k = 2; k <= CAP; k <<= 1) {
    for (int j = k >> 1; j > 0; j >>= 1) {
      for (int i = threadIdx.x; i < CAP; i += 1024) {
        int ixj = i ^ j;
        if (ixj > i) {
          unsigned long long a = sh[i], c = sh[ixj];
          bool up = ((i & k) == 0);
          if ((a > c) == up) { sh[i] = c; sh[ixj] = a; }
        }
      }
      __syncthreads();
    }
  }
  for (int r = threadIdx.x; r < KSEL; r += 1024) {
    int a = (int)(unsigned int)sh[r];
    float4 anc = anchors4[(size_t)b * NA + a];
    float4 d   = bbox4[(size_t)b * NA + a];
    float h = anc.z - anc.x;
    float w = anc.w - anc.y;
    float dy = d.x * 0.1f, dx = d.y * 0.1f, dh = d.z * 0.2f, dw = d.w * 0.2f;
    float cy = (anc.x + (0.5f * h)) + (dy * h);
    float cx = (anc.y + (0.5f * w)) + (dx * w);
    float h2 = h * expf(dh);
    float w2 = w * expf(dw);
    float y1 = cy - 0.5f * h2;
    float x1 = cx - 0.5f * w2;
    float y2 = y1 + h2;
    float x2 = x1 + w2;
    y1 = fminf(fmaxf(y1, 0.f), 1.f);
    x1 = fminf(fmaxf(x1, 0.f), 1.f);
    y2 = fminf(fmaxf(y2, 0.f), 1.f);
    x2 = fminf(fmaxf(x2, 0.f), 1.f);
    boxes4[(size_t)b * KSEL + r] = make_float4(y1, x1, y2, x2);
  }
}

// ---------------- 5. suppression mask matrix (transposed: [b][colblock][row]) ----------------
__global__ __launch_bounds__(64) void mask_kernel(const float4* __restrict__ boxes4,
                                                  unsigned long long* __restrict__ maskT) {
#pragma clang fp contract(off)
  int cb = blockIdx.x, rb = blockIdx.y, b = blockIdx.z;
  if (cb < rb) return;   // lower-triangle words never read by the scan
  __shared__ float4 cols[64];
  int c0 = cb * 64;
  int c = c0 + threadIdx.x;
  cols[threadIdx.x] = (c < KSEL) ? boxes4[(size_t)b * KSEL + c] : make_float4(0.f, 0.f, 0.f, 0.f);
  __syncthreads();
  int row = rb * 64 + threadIdx.x;
  if (row >= KSEL) return;
  float4 r = boxes4[(size_t)b * KSEL + row];
  float ra = (r.z - r.x) * (r.w - r.y);
  unsigned long long bits = 0ull;
  int nmax = min(64, KSEL - c0);
  for (int u = 0; u < nmax; ++u) {
    int cc = c0 + u;
    if (cc <= row) continue;
    float4 cb4 = cols[u];
    float ca = (cb4.z - cb4.x) * (cb4.w - cb4.y);
    float ih = fmaxf(fminf(r.z, cb4.z) - fmaxf(r.x, cb4.x), 0.f);
    float iw = fmaxf(fminf(r.w, cb4.w) - fmaxf(r.y, cb4.y), 0.f);
    float inter = ih * iw;
    float uni = (ra + ca) - inter;
    float iou = (uni > 0.f) ? (inter / uni) : 0.f;
    if (iou > 0.7f) bits |= (1ull << u);
  }
  maskT[((size_t)b * NB + cb) * KSEL + row] = bits;
}

// ---------------- 6. serial greedy scan + output ----------------
__global__ __launch_bounds__(256) void scan_kernel(const float4* __restrict__ boxes4,
                                                   const unsigned long long* __restrict__ maskT,
                                                   float4* __restrict__ out4) {
  __shared__ unsigned long long sbuf[2][CH][NB];
  __shared__ unsigned long long ssup[NB];
  __shared__ int skeep[PROP];
  __shared__ int s_state[2]; // [0]=kept, [1]=done
  int b = blockIdx.x;
  int tid = threadIdx.x;
  for (int i = tid; i < NB; i += 256) ssup[i] = 0ull;
  if (tid == 0) { s_state[0] = 0; s_state[1] = 0; }
  // stage chunk 0
  for (int idx = tid; idx < NB * CH; idx += 256) {
    int jw = idx / CH, u = idx % CH;
    sbuf[0][u][jw] = maskT[((size_t)b * NB + jw) * KSEL + u];
  }
  __syncthreads();
  for (int c = 0; c < NCH; ++c) {
    int cur = c & 1;
    if (tid >= 64) {
      // waves 1-3: stage chunk c+1
      int nc = c + 1;
      if (nc < NCH) {
        int base = nc * CH;
        int nrows = min(CH, KSEL - base);
        for (int idx = tid - 64; idx < NB * nrows; idx += 192) {
          int jw = idx / nrows, u = idx % nrows;
          sbuf[cur ^ 1][u][jw] = maskT[((size_t)b * NB + jw) * KSEL + base + u];
        }
      }
    } else {
      // wave 0: serial greedy over chunk c
      int base = c * CH;
      int cword = base >> 6;        // constant within chunk (CH divides 64)
      int lane = tid;
      unsigned long long cw = ssup[cword];
      int kept = s_state[0];
      int done = 0;
      int nrows = min(CH, KSEL - base);
#pragma unroll
      for (int u = 0; u < CH; ++u) {
        if (u >= nrows) break;
        unsigned long long dw = sbuf[cur][u][cword];
        int i = base + u;
        int bit = i & 63;
        if (!((cw >> bit) & 1ull)) {
          if (lane == 0) skeep[kept] = i;
          kept++;
          if (kept >= PROP) { done = 1; break; }
          int jw = cword + lane;
          if (jw < NB) ssup[jw] |= sbuf[cur][u][jw];
          int jw2 = jw + 64;
          if (jw2 < NB) ssup[jw2] |= sbuf[cur][u][jw2];
          cw |= dw;
        }
      }
      if (lane == 0) {
        s_state[0] = kept;
        if (done || c == NCH - 1) s_state[1] = 1;
      }
    }
    __syncthreads();
    if (s_state[1]) break;
  }
  __syncthreads();
  int kept = s_state[0];
  for (int r = tid; r < PROP; r += 256) {
    float4 v = make_float4(0.f, 0.f, 0.f, 0.f);
    if (r < kept) v = boxes4[(size_t)b * KSEL + skeep[r]];
    out4[(size_t)b * PROP + r] = v;
  }
}

// ---------------- launch ----------------
extern "C" void kernel_launch(void* const* d_in, const int* in_sizes, int n_in,
                              void* d_out, int out_size, void* d_ws, size_t ws_size,
                              hipStream_t stream) {
  const float2* probs   = (const float2*)d_in[0];
  const float4* bbox4   = (const float4*)d_in[1];
  const float4* anchors4= (const float4*)d_in[2];
  float4* out4 = (float4*)d_out;
  char* ws = (char*)d_ws;

  int* cnt                  = (int*)(ws + OFF_CNT);
  int* tsel                 = (int*)(ws + OFF_TSEL);
  unsigned long long* keys  = (unsigned long long*)(ws + OFF_KEYS);
  float4* boxes4            = (float4*)(ws + OFF_BOXES);
  unsigned long long* maskT = (unsigned long long*)(ws + OFF_MASK);
  unsigned int* hist        = (unsigned int*)(ws + OFF_HIST); // aliases mask region

  // zero the per-batch counters only (hist is written non-atomically in full)
  hipMemsetAsync(ws + OFF_CNT, 0, 512, stream);

  hipLaunchKernelGGL(hist_kernel,    dim3(HB, BATCH),     dim3(256),  0, stream, probs, hist);
  hipLaunchKernelGGL(thresh_kernel,  dim3(BATCH),         dim3(256),  0, stream, hist, tsel);
  hipLaunchKernelGGL(compact_kernel, dim3(128, BATCH),    dim3(256),  0, stream, probs, tsel, cnt, keys);
  hipLaunchKernelGGL(sortbox_kernel, dim3(BATCH),         dim3(1024), 0, stream, anchors4, bbox4, cnt, keys, boxes4);
  hipLaunchKernelGGL(mask_kernel,    dim3(NB, NB, BATCH), dim3(64),   0, stream, boxes4, maskT);
  hipLaunchKernelGGL(scan_kernel,    dim3(BATCH),         dim3(256),  0, stream, boxes4, maskT, out4);
}

// Round 3
// 510.624 us; speedup vs baseline: 1.5679x; 1.0043x over previous
//
#include <hip/hip_runtime.h>
#include <hip/hip_bf16.h>

// ---------------- problem constants ----------------
constexpr int BATCH = 8;
constexpr int NA    = 261888;
constexpr int KSEL  = 6000;          // PRE_NMS_LIMIT
constexpr int KSELP = 6016;          // rows padded to multiple of CH (pow2 staging math)
constexpr int PROP  = 1000;          // PROPOSAL_COUNT
constexpr int CAP   = 8192;          // candidate capacity (pow2 for bitonic)
constexpr int NBINS = 8192;          // histogram bins
constexpr int HB    = 16;            // private histogram blocks per batch
constexpr int NB    = (KSEL + 63) / 64;   // 94 mask words per row
constexpr int NBP   = 96;            // padded word-dim for LDS staging (192*16/32)
constexpr int CH    = 32;            // scan chunk rows
constexpr int NCH   = KSELP / CH;    // 188

// workspace layout (bytes) — hist ALIASES mask region (disjoint liveness)
constexpr size_t OFF_CNT   = 0;                                   // 8*16*4 = 512
constexpr size_t OFF_TSEL  = 512;                                 // 32
constexpr size_t OFF_KEYS  = 544;                                 // 8*8192*8 = 524288
constexpr size_t OFF_BOXES = 524832;                              // 8*6000*16 = 768000
constexpr size_t OFF_MASK  = 1292832;                             // 8*94*6016*8 = 36191232
constexpr size_t OFF_HIST  = OFF_MASK;                            // 8*16*8192*4 = 4MB (aliased)
// total ~35.7 MiB

__device__ __forceinline__ int score_bin(float s) {
  int b = (int)(s * (float)NBINS);
  if (b < 0) b = 0;
  if (b > NBINS - 1) b = NBINS - 1;
  return b;
}

// ---------------- 1. histogram (private per-block copies, no global atomics) ----------------
__global__ __launch_bounds__(256) void hist_kernel(const float2* __restrict__ probs,
                                                   unsigned int* __restrict__ hist) {
  __shared__ unsigned int lh[NBINS];
  for (int i = threadIdx.x; i < NBINS; i += 256) lh[i] = 0u;
  __syncthreads();
  int b = blockIdx.y;
  const float2* p = probs + (size_t)b * NA;
  for (int a = blockIdx.x * 256 + threadIdx.x; a < NA; a += HB * 256) {
    atomicAdd(&lh[score_bin(p[a].y)], 1u);
  }
  __syncthreads();
  unsigned int* gh = hist + ((size_t)b * HB + blockIdx.x) * NBINS;
  for (int i = threadIdx.x; i < NBINS; i += 256) gh[i] = lh[i];
}

// ---------------- 2. threshold bin select ----------------
__global__ __launch_bounds__(256) void thresh_kernel(const unsigned int* __restrict__ hist,
                                                     int* __restrict__ tsel) {
  constexpr int GR = NBINS / 256; // 32 bins per thread
  __shared__ unsigned int ch[NBINS];
  __shared__ unsigned int gsum[256];
  int b = blockIdx.x;
  const unsigned int* h = hist + (size_t)b * HB * NBINS;
  for (int bin = threadIdx.x; bin < NBINS; bin += 256) {
    unsigned int s = 0;
    for (int k = 0; k < HB; ++k) s += h[(size_t)k * NBINS + bin];
    ch[bin] = s;
  }
  __syncthreads();
  unsigned int s = 0;
  int g0 = threadIdx.x * GR;
  for (int i = 0; i < GR; ++i) s += ch[g0 + i];
  gsum[threadIdx.x] = s;
  __syncthreads();
  if (threadIdx.x == 0) {
    unsigned int acc = 0;
    int g = 255;
    for (; g > 0; --g) {
      if (acc + gsum[g] >= (unsigned)KSEL) break;
      acc += gsum[g];
    }
    int t = g * GR;
    for (int bin = g * GR + GR - 1; bin >= g * GR; --bin) {
      acc += ch[bin];
      if (acc >= (unsigned)KSEL) { t = bin; break; }
    }
    tsel[b] = t;
  }
}

// ---------------- 3. compact candidates (block-aggregated, 1 global atomic/block) ----------------
__global__ __launch_bounds__(256) void compact_kernel(const float2* __restrict__ probs,
                                                      const int* __restrict__ tsel,
                                                      int* __restrict__ cnt,
                                                      unsigned long long* __restrict__ keys) {
  __shared__ int lcnt, lbase;
  __shared__ unsigned long long lbuf[2048]; // block covers <=2048 anchors
  int b = blockIdx.y;
  int t = tsel[b];
  if (threadIdx.x == 0) lcnt = 0;
  __syncthreads();
  const float2* p = probs + (size_t)b * NA;
  for (int a = blockIdx.x * blockDim.x + threadIdx.x; a < NA; a += gridDim.x * blockDim.x) {
    float s = p[a].y;
    if (score_bin(s) >= t) {
      int pos = atomicAdd(&lcnt, 1);
      unsigned int ib = ~__float_as_uint(s); // score>=0: ~bits ascending == score descending
      lbuf[pos] = ((unsigned long long)ib << 32) | (unsigned int)a;
    }
  }
  __syncthreads();
  if (threadIdx.x == 0) lbase = atomicAdd(&cnt[b * 16], lcnt);
  __syncthreads();
  int n = lcnt, base = lbase;
  unsigned long long* kb = keys + (size_t)b * CAP;
  for (int i = threadIdx.x; i < n; i += 256) {
    int pos = base + i;
    if (pos < CAP) kb[pos] = lbuf[i];
  }
}

// ---------------- 4. bitonic sort + box decode ----------------
__global__ __launch_bounds__(1024) void sortbox_kernel(const float4* __restrict__ anchors4,
                                                       const float4* __restrict__ bbox4,
                                                       const int* __restrict__ cnt,
                                                       const unsigned long long* __restrict__ keys,
                                                       float4* __restrict__ boxes4) {
#pragma clang fp contract(off)
  __shared__ unsigned long long sh[CAP];
  int b = blockIdx.x;
  int n = cnt[b * 16];
  if (n > CAP) n = CAP;
  const unsigned long long* kb = keys + (size_t)b * CAP;
  for (int i = threadIdx.x; i < CAP; i += 1024) sh[i] = (i < n) ? kb[i] : ~0ull;
  __syncthreads();
  for (int k = 2; k <= CAP; k <<= 1) {
    for (int j = k >> 1; j > 0; j >>= 1) {
      for (int i = threadIdx.x; i < CAP; i += 1024) {
        int ixj = i ^ j;
        if (ixj > i) {
          unsigned long long a = sh[i], c = sh[ixj];
          bool up = ((i & k) == 0);
          if ((a > c) == up) { sh[i] = c; sh[ixj] = a; }
        }
      }
      __syncthreads();
    }
  }
  for (int r = threadIdx.x; r < KSEL; r += 1024) {
    int a = (int)(unsigned int)sh[r];
    float4 anc = anchors4[(size_t)b * NA + a];
    float4 d   = bbox4[(size_t)b * NA + a];
    float h = anc.z - anc.x;
    float w = anc.w - anc.y;
    float dy = d.x * 0.1f, dx = d.y * 0.1f, dh = d.z * 0.2f, dw = d.w * 0.2f;
    float cy = (anc.x + (0.5f * h)) + (dy * h);
    float cx = (anc.y + (0.5f * w)) + (dx * w);
    float h2 = h * expf(dh);
    float w2 = w * expf(dw);
    float y1 = cy - 0.5f * h2;
    float x1 = cx - 0.5f * w2;
    float y2 = y1 + h2;
    float x2 = x1 + w2;
    y1 = fminf(fmaxf(y1, 0.f), 1.f);
    x1 = fminf(fmaxf(x1, 0.f), 1.f);
    y2 = fminf(fmaxf(y2, 0.f), 1.f);
    x2 = fminf(fmaxf(x2, 0.f), 1.f);
    boxes4[(size_t)b * KSEL + r] = make_float4(y1, x1, y2, x2);
  }
}

// ---------------- 5. suppression mask matrix (transposed: [b][colblock][row], row-stride KSELP) ----------------
__global__ __launch_bounds__(64) void mask_kernel(const float4* __restrict__ boxes4,
                                                  unsigned long long* __restrict__ maskT) {
#pragma clang fp contract(off)
  int cb = blockIdx.x, rb = blockIdx.y, b = blockIdx.z;
  if (cb < rb) return;   // lower-triangle words never read by the scan
  __shared__ float4 cols[64];
  int c0 = cb * 64;
  int c = c0 + threadIdx.x;
  cols[threadIdx.x] = (c < KSEL) ? boxes4[(size_t)b * KSEL + c] : make_float4(0.f, 0.f, 0.f, 0.f);
  __syncthreads();
  int row = rb * 64 + threadIdx.x;
  if (row >= KSEL) return;
  float4 r = boxes4[(size_t)b * KSEL + row];
  float ra = (r.z - r.x) * (r.w - r.y);
  unsigned long long bits = 0ull;
  int nmax = min(64, KSEL - c0);
  for (int u = 0; u < nmax; ++u) {
    int cc = c0 + u;
    if (cc <= row) continue;
    float4 cb4 = cols[u];
    float ca = (cb4.z - cb4.x) * (cb4.w - cb4.y);
    float ih = fmaxf(fminf(r.z, cb4.z) - fmaxf(r.x, cb4.x), 0.f);
    float iw = fmaxf(fminf(r.w, cb4.w) - fmaxf(r.y, cb4.y), 0.f);
    float inter = ih * iw;
    float uni = (ra + ca) - inter;
    float iou = (uni > 0.f) ? (inter / uni) : 0.f;
    if (iou > 0.7f) bits |= (1ull << u);
  }
  maskT[((size_t)b * NB + cb) * KSELP + row] = bits;
}

// ---------------- 6. serial greedy scan + output ----------------
// wave 0 scans; waves 1-3 reg-stage with prefetch depth 2.
// LDS chunk layout: sbuf[buf][jw][u ^ (jw&31)]  (global-coalesced, conflict-free writes)
__global__ __launch_bounds__(256) void scan_kernel(const float4* __restrict__ boxes4,
                                                   const unsigned long long* __restrict__ maskT,
                                                   float4* __restrict__ out4) {
  __shared__ unsigned long long sbuf[2][NBP][CH];  // 48 KB
  __shared__ unsigned long long ssup[NB];
  __shared__ int skeep[PROP];
  __shared__ int s_kept;
  __shared__ int s_done;
  int b = blockIdx.x;
  int tid = threadIdx.x;
  for (int i = tid; i < NB; i += 256) ssup[i] = 0ull;
  if (tid == 0) { s_kept = 0; s_done = 0; }
  const unsigned long long* mb = maskT + (size_t)b * NB * KSELP;

  unsigned long long r[16];
  int lin0 = tid - 64;
  if (tid >= 64) {
    // prologue: chunk 0 -> LDS buf0; issue chunk 1 loads into regs
#pragma unroll
    for (int k = 0; k < 16; ++k) {
      int lin = lin0 + k * 192;
      int jw = lin >> 5, u = lin & 31;
      r[k] = (jw < NB) ? mb[(size_t)jw * KSELP + u] : 0ull;
    }
#pragma unroll
    for (int k = 0; k < 16; ++k) {
      int lin = lin0 + k * 192;
      int jw = lin >> 5, u = lin & 31;
      sbuf[0][jw][u ^ (jw & 31)] = r[k];
    }
#pragma unroll
    for (int k = 0; k < 16; ++k) {
      int lin = lin0 + k * 192;
      int jw = lin >> 5, u = lin & 31;
      r[k] = (jw < NB) ? mb[(size_t)jw * KSELP + CH + u] : 0ull;
    }
  }
  __syncthreads();

  int kept = 0;
  for (int c = 0; c < NCH; ++c) {
    int rb = c & 1;
    if (tid >= 64) {
      if (c + 1 < NCH) {
#pragma unroll
        for (int k = 0; k < 16; ++k) {
          int lin = lin0 + k * 192;
          int jw = lin >> 5, u = lin & 31;
          sbuf[rb ^ 1][jw][u ^ (jw & 31)] = r[k];
        }
      }
      if (c + 2 < NCH) {
        int base2 = (c + 2) * CH;
#pragma unroll
        for (int k = 0; k < 16; ++k) {
          int lin = lin0 + k * 192;
          int jw = lin >> 5, u = lin & 31;
          r[k] = (jw < NB) ? mb[(size_t)jw * KSELP + base2 + u] : 0ull;
        }
      }
    } else {
      int base = c * CH;
      int nrows = min(CH, KSEL - base);
      int cword = base >> 6;
      int sh = base & 63;
      int cx = cword & 31;
      // broadcast pre-read of this chunk's decision words (batched, off-chain after one latency)
      unsigned long long d[CH];
#pragma unroll
      for (int u = 0; u < CH; ++u) d[u] = sbuf[rb][cword][u ^ cx];
      unsigned long long cw = ssup[cword];
      unsigned keepm = 0u;
      int done = 0;
      // pure-register uniform serial decision loop
#pragma unroll
      for (int u = 0; u < CH; ++u) {
        if (u >= nrows) break;
        if (!((cw >> (sh + u)) & 1ull)) {
          keepm |= (1u << u);
          cw |= d[u];
          ++kept;
          if (kept >= PROP) { done = 1; break; }
        }
      }
      int lane = tid;
      // parallel skeep write via popcount rank
      int kbase = kept - __popc(keepm);
      if (lane < CH && ((keepm >> lane) & 1u)) {
        int rank = __popc(keepm & ((1u << lane) - 1));
        skeep[kbase + rank] = base + lane;
      }
      // parallel ssup |= OR over kept rows (unrolled independent reads, cndmask select)
      if (!done) {
        int jw = cword + lane;
        if (jw < NB) {
          int jx = jw & 31;
          unsigned long long acc = 0ull;
#pragma unroll
          for (int u = 0; u < CH; ++u) {
            unsigned long long v = sbuf[rb][jw][u ^ jx];
            acc |= (((keepm >> u) & 1u) ? v : 0ull);
          }
          ssup[jw] |= acc;
          int jw2 = jw + 64;
          if (jw2 < NB) {
            int jx2 = jw2 & 31;
            unsigned long long acc2 = 0ull;
#pragma unroll
            for (int u = 0; u < CH; ++u) {
              unsigned long long v = sbuf[rb][jw2][u ^ jx2];
              acc2 |= (((keepm >> u) & 1u) ? v : 0ull);
            }
            ssup[jw2] |= acc2;
          }
        }
      }
      if (lane == 0 && (done || c == NCH - 1)) { s_kept = kept; s_done = 1; }
    }
    __syncthreads();
    if (s_done) break;
  }

  int fin = s_kept;
  for (int rr = tid; rr < PROP; rr += 256) {
    float4 v = make_float4(0.f, 0.f, 0.f, 0.f);
    if (rr < fin) v = boxes4[(size_t)b * KSEL + skeep[rr]];
    out4[(size_t)b * PROP + rr] = v;
  }
}

// ---------------- launch ----------------
extern "C" void kernel_launch(void* const* d_in, const int* in_sizes, int n_in,
                              void* d_out, int out_size, void* d_ws, size_t ws_size,
                              hipStream_t stream) {
  const float2* probs   = (const float2*)d_in[0];
  const float4* bbox4   = (const float4*)d_in[1];
  const float4* anchors4= (const float4*)d_in[2];
  float4* out4 = (float4*)d_out;
  char* ws = (char*)d_ws;

  int* cnt                  = (int*)(ws + OFF_CNT);
  int* tsel                 = (int*)(ws + OFF_TSEL);
  unsigned long long* keys  = (unsigned long long*)(ws + OFF_KEYS);
  float4* boxes4            = (float4*)(ws + OFF_BOXES);
  unsigned long long* maskT = (unsigned long long*)(ws + OFF_MASK);
  unsigned int* hist        = (unsigned int*)(ws + OFF_HIST); // aliases mask region

  hipMemsetAsync(ws + OFF_CNT, 0, 512, stream);

  hipLaunchKernelGGL(hist_kernel,    dim3(HB, BATCH),     dim3(256),  0, stream, probs, hist);
  hipLaunchKernelGGL(thresh_kernel,  dim3(BATCH),         dim3(256),  0, stream, hist, tsel);
  hipLaunchKernelGGL(compact_kernel, dim3(128, BATCH),    dim3(256),  0, stream, probs, tsel, cnt, keys);
  hipLaunchKernelGGL(sortbox_kernel, dim3(BATCH),         dim3(1024), 0, stream, anchors4, bbox4, cnt, keys, boxes4);
  hipLaunchKernelGGL(mask_kernel,    dim3(NB, NB, BATCH), dim3(64),   0, stream, boxes4, maskT);
  hipLaunchKernelGGL(scan_kernel,    dim3(BATCH),         dim3(256),  0, stream, boxes4, maskT, out4);
}